// Round 4
// baseline (738.736 us; speedup 1.0000x reference)
//
#include <hip/hip_runtime.h>
#include <math.h>

#define ROWS 65536
#define DIM  256
#define KC   1024
#define NQ   (ROWS * DIM)

// ---- ws layout (bytes) ----
// [0]      double lossacc
// [16]     int    counts[1024]          (ends 4112)
// [4224]   float  B32[1024]             (ends 8320)
// [8320]   float  Arr[65536]            (ends 270464)
// [270464] u64    packed[65536]         (ends 794752)   (distbits<<32)|idx

// ---------------------------------------------------------------------------
// Wave-cooperative numpy pairwise sum-of-squares: 16 lanes per row.
// Lane (h,l) owns numpy accumulator r_l of half h: chain over a[h*128+8k+l],
// k ascending — exactly numpy's 8-accumulator unrolled loop. Combine with
// shfl_xor in numpy's tree order (fp32 add is commutative, so operand order
// within each fadd doesn't change rounding):
//   step1: s01,s23,s45,s67; step2: (s01+s23)+(s45+s67); step3: h0+h1.
// ---------------------------------------------------------------------------
__global__ __launch_bounds__(256) void k_prep16(const float* __restrict__ src,
                                                float* __restrict__ dst,
                                                int nrows) {
    int lane = threadIdx.x & 63;
    int wv   = threadIdx.x >> 6;
    int rg   = lane >> 4;            // row within wave's group of 4
    int sub  = lane & 15;
    int h    = sub >> 3;             // half (0/1)
    int l    = sub & 7;              // numpy accumulator id
    int row  = blockIdx.x * 16 + wv * 4 + rg;
    if (row >= nrows) return;        // nrows % 16 == 0 -> wave-uniform
    const float* a = src + (size_t)row * DIM + h * 128 + l;
    float x = a[0];
    float r = __fmul_rn(x, x);
#pragma unroll
    for (int k = 1; k < 16; ++k) {
        float y = a[8 * k];
        r = __fadd_rn(r, __fmul_rn(y, y));
    }
    float t;
    t = __shfl_xor(r, 1, 64);  r = __fadd_rn(r, t);   // s01/s23/s45/s67
    t = __shfl_xor(r, 2, 64);  r = __fadd_rn(r, t);   // (s01+s23) etc.
    t = __shfl_xor(r, 4, 64);  r = __fadd_rn(r, t);   // half total
    t = __shfl_xor(r, 8, 64);  r = __fadd_rn(r, t);   // h0 + h1
    if (sub == 0) dst[row] = r;
}

// ---------------- K1: fp32 dist + first-index argmin -----------------------
// Split-K: blockIdx.y in {0,1} handles cols [y*512, y*512+512).
// Tiles: 128 rows x 128 cols per cb iter, D in chunks of 32.
// LDS: row-major [r][d]/[c][d], stride 36 floats: b128 staging writes are
// conflict-free; fragment reads are wave-broadcast (x: 16-way, e: 4-way).
// Each acc[i][j] is ONE ascending-d fmaf chain from 0 over d=0..255 ->
// bit-identical to OpenBLAS sgemm per-element accumulation (x2 exact).
// NOTE: no min-waves clause in launch_bounds — R3's (256,4) clamped VGPRs
// to 64 and spilled the accumulator (WRITE_SIZE 0.25->606 MB).
#define TM 128
#define TN 128
#define TD 32
#define STR 36          // floats; 144 B row stride, 16B-aligned

__global__ __launch_bounds__(256) void k_pass1(
    const float* __restrict__ X, const float* __restrict__ E,
    const float* __restrict__ B32, const float* __restrict__ Arr,
    unsigned long long* __restrict__ packed)
{
    __shared__ float sm[2 * TM * STR];   // 36864 B -> 4 blocks/CU
    float* Xs = sm;                      // [128][36]
    float* Es = sm + TM * STR;           // [128][36]

    const int tid = threadIdx.x;
    const int tx = tid & 15;
    const int ty = tid >> 4;
    const int rowbase = blockIdx.x * TM;
    const int colbase = blockIdx.y * 512;

    float a8[8];
#pragma unroll
    for (int i = 0; i < 8; ++i) a8[i] = Arr[rowbase + ty + 16 * i];

    float v1[8]; int i1[8];
#pragma unroll
    for (int i = 0; i < 8; ++i) { v1[i] = 3.0e38f; i1[i] = 0; }

    for (int cb = 0; cb < 512; cb += TN) {
        float acc[8][8];
#pragma unroll
        for (int i = 0; i < 8; ++i)
#pragma unroll
            for (int j = 0; j < 8; ++j) acc[i][j] = 0.0f;

        for (int dc = 0; dc < DIM; dc += TD) {
            __syncthreads();
            // stage 128x32 of X and E, row-major stride-36, b128 writes
#pragma unroll
            for (int k = 0; k < 4; ++k) {
                int fi = tid + k * 256;            // 0..1023
                int r  = fi >> 3;                  // 0..127
                int g4 = (fi & 7) * 4;             // 0,4,...,28
                float4 xv = *(const float4*)(X + (size_t)(rowbase + r) * DIM + dc + g4);
                *(float4*)&Xs[r * STR + g4] = xv;
                float4 ev = *(const float4*)(E + (size_t)(colbase + cb + r) * DIM + dc + g4);
                *(float4*)&Es[r * STR + g4] = ev;
            }
            __syncthreads();

            // compute: 8 groups of 4 d's; fragments read as float4 along d
#pragma unroll
            for (int gg = 0; gg < 8; ++gg) {
                float4 e4[8];
#pragma unroll
                for (int j = 0; j < 8; ++j)
                    e4[j] = *(float4*)&Es[(tx + 16 * j) * STR + gg * 4];
#pragma unroll
                for (int i = 0; i < 8; ++i) {
                    float4 x4 = *(float4*)&Xs[(ty + 16 * i) * STR + gg * 4];
#pragma unroll
                    for (int j = 0; j < 8; ++j) {
                        acc[i][j] = fmaf(x4.x, e4[j].x, acc[i][j]);
                        acc[i][j] = fmaf(x4.y, e4[j].y, acc[i][j]);
                        acc[i][j] = fmaf(x4.z, e4[j].z, acc[i][j]);
                        acc[i][j] = fmaf(x4.w, e4[j].w, acc[i][j]);
                    }
                }
            }
        }

        // fold: dist = fl(fl(A + B) - fl(2*dot)), numpy rounding; strict <
        // keeps lowest c per thread (c ascends with j and cb).
#pragma unroll
        for (int j = 0; j < 8; ++j) {
            int c = colbase + cb + tx + 16 * j;
            float b = B32[c];
#pragma unroll
            for (int i = 0; i < 8; ++i) {
                float Cv  = __fmul_rn(2.0f, acc[i][j]);
                float t1v = __fadd_rn(a8[i], b);
                float dv  = __fsub_rn(t1v, Cv);
                if (dv < v1[i]) { v1[i] = dv; i1[i] = c; }
            }
        }
    }

    // merge (val, idx) across the 16 col-threads per row via LDS
    __syncthreads();
    float* Mv = sm;                        // [128][16] floats
    int*   Mi = (int*)(sm + 2048);         // [128][16] ints
#pragma unroll
    for (int i = 0; i < 8; ++i) {
        int r = ty + 16 * i;
        Mv[r * 16 + tx] = v1[i];
        Mi[r * 16 + tx] = i1[i];
    }
    __syncthreads();
    if (tid < TM) {
        int r = tid;
        float bv = Mv[r * 16];
        int   bi = Mi[r * 16];
        for (int t = 1; t < 16; ++t) {
            float av = Mv[r * 16 + t];
            int   ai = Mi[r * 16 + t];
            if (av < bv || (av == bv && ai < bi)) { bv = av; bi = ai; }
        }
        // dist > 0 always (A ~ 256 dominates) -> IEEE bits order-preserving;
        // ties resolve to lower idx -> global first-index semantics.
        unsigned long long pk =
            ((unsigned long long)__float_as_uint(bv) << 32) |
            (unsigned long long)(unsigned)bi;
        atomicMin(&packed[rowbase + r], pk);
    }
}

// ---------------- K3: gather quantized + fp64 loss accumulation ------------
__global__ __launch_bounds__(256) void k_out(
    const float* __restrict__ X, const float* __restrict__ E,
    const unsigned long long* __restrict__ packed, float* __restrict__ out0,
    double* __restrict__ lossacc)
{
    const int NF4 = NQ / 4;
    double s = 0.0;
    for (int g = blockIdx.x * blockDim.x + threadIdx.x; g < NF4;
         g += gridDim.x * blockDim.x) {
        int row = g >> 6;
        int d4  = g & 63;
        int j = (int)(packed[row] & 0xffffffffULL);
        float4 q = *(const float4*)(E + (size_t)j * DIM + d4 * 4);
        float4 x = *(const float4*)(X + (size_t)g * 4);
        *(float4*)(out0 + (size_t)g * 4) = q;
        double dx;
        dx = (double)q.x - (double)x.x; s = fma(dx, dx, s);
        dx = (double)q.y - (double)x.y; s = fma(dx, dx, s);
        dx = (double)q.z - (double)x.z; s = fma(dx, dx, s);
        dx = (double)q.w - (double)x.w; s = fma(dx, dx, s);
    }
#pragma unroll
    for (int off = 32; off > 0; off >>= 1) s += __shfl_down(s, off, 64);
    __shared__ double wsum[4];
    int lane = threadIdx.x & 63, wv = threadIdx.x >> 6;
    if (lane == 0) wsum[wv] = s;
    __syncthreads();
    if (threadIdx.x == 0) {
        double t = wsum[0] + wsum[1] + wsum[2] + wsum[3];
        atomicAdd(lossacc, t);
    }
}

// ---------------- K3b: index output + histogram ----------------------------
__global__ __launch_bounds__(256) void k_idxout(
    const unsigned long long* __restrict__ packed, float* __restrict__ out1,
    int* __restrict__ counts)
{
    __shared__ int h[KC];
    for (int i = threadIdx.x; i < KC; i += 256) h[i] = 0;
    __syncthreads();
    int r = blockIdx.x * 256 + threadIdx.x;   // grid 256*256 = 65536 exact
    int j = (int)(packed[r] & 0xffffffffULL);
    out1[r] = (float)j;
    atomicAdd(&h[j], 1);
    __syncthreads();
    for (int i = threadIdx.x; i < KC; i += 256)
        if (h[i]) atomicAdd(&counts[i], h[i]);
}

// ---------------- K4: perplexity + loss finalize ---------------------------
__global__ void k_fin(const int* __restrict__ counts,
                      const double* __restrict__ lossacc,
                      float* __restrict__ out_pl)
{
    __shared__ double sh[256];
    double s = 0.0;
    for (int i = threadIdx.x; i < KC; i += 256) {
        double p = (double)counts[i] / 65536.0;
        s += p * log(p + 1.1920928955078125e-07);   // EPS = fp32 eps exactly
    }
    sh[threadIdx.x] = s;
    __syncthreads();
    for (int off = 128; off > 0; off >>= 1) {
        if (threadIdx.x < off) sh[threadIdx.x] += sh[threadIdx.x + off];
        __syncthreads();
    }
    if (threadIdx.x == 0) {
        out_pl[0] = (float)exp(-sh[0]);
        out_pl[1] = (float)((*lossacc / (double)NQ) * 1.1);  // q + 0.1*e
    }
}

extern "C" void kernel_launch(void* const* d_in, const int* in_sizes, int n_in,
                              void* d_out, int out_size, void* d_ws, size_t ws_size,
                              hipStream_t stream) {
    const float* X = (const float*)d_in[0];
    const float* E = (const float*)d_in[1];
    float* out = (float*)d_out;
    char* ws = (char*)d_ws;

    double* lossacc = (double*)(ws + 0);
    int*    counts  = (int*)(ws + 16);
    float*  B32     = (float*)(ws + 4224);
    float*  Arr     = (float*)(ws + 8320);
    unsigned long long* packed = (unsigned long long*)(ws + 270464);

    hipMemsetAsync(ws, 0, 4224, stream);               // lossacc + counts
    hipMemsetAsync(ws + 270464, 0xFF, 524288, stream); // packed = u64 max

    hipLaunchKernelGGL(k_prep16, dim3(KC / 16),   dim3(256), 0, stream,
                       E, B32, KC);
    hipLaunchKernelGGL(k_prep16, dim3(ROWS / 16), dim3(256), 0, stream,
                       X, Arr, ROWS);
    hipLaunchKernelGGL(k_pass1, dim3(ROWS / TM, 2), dim3(256), 0, stream,
                       X, E, B32, Arr, packed);
    hipLaunchKernelGGL(k_out,   dim3(2048), dim3(256), 0, stream,
                       X, E, packed, out, lossacc);
    hipLaunchKernelGGL(k_idxout, dim3(256), dim3(256), 0, stream,
                       packed, out + NQ, counts);
    hipLaunchKernelGGL(k_fin,   dim3(1),   dim3(256), 0, stream,
                       counts, lossacc, out + NQ + 65536);
}

// Round 6
// 625.188 us; speedup vs baseline: 1.1816x; 1.1816x over previous
//
#include <hip/hip_runtime.h>
#include <math.h>

#define ROWS 65536
#define DIM  256
#define KC   1024
#define NQ   (ROWS * DIM)

// ---- ws layout (bytes) ----
// [0]      double lossacc
// [16]     int    counts[1024]          (ends 4112)
// [4224]   float  B32[1024]             (ends 8320)
// [8320]   float  Arr[65536]            (ends 270464)
// [270464] u64    packed[65536]         (ends 794752)   (distbits<<32)|idx

// ---------------------------------------------------------------------------
// Wave-cooperative numpy pairwise sum-of-squares: 16 lanes per row (verified
// bit-exact in R4). Lane (h,l) owns numpy accumulator r_l of half h; combine
// via shfl_xor in numpy's tree order (fp32 add commutative).
// ---------------------------------------------------------------------------
__global__ __launch_bounds__(256) void k_prep16(const float* __restrict__ src,
                                                float* __restrict__ dst,
                                                int nrows) {
    int lane = threadIdx.x & 63;
    int wv   = threadIdx.x >> 6;
    int rg   = lane >> 4;
    int sub  = lane & 15;
    int h    = sub >> 3;
    int l    = sub & 7;
    int row  = blockIdx.x * 16 + wv * 4 + rg;
    if (row >= nrows) return;
    const float* a = src + (size_t)row * DIM + h * 128 + l;
    float x = a[0];
    float r = __fmul_rn(x, x);
#pragma unroll
    for (int k = 1; k < 16; ++k) {
        float y = a[8 * k];
        r = __fadd_rn(r, __fmul_rn(y, y));
    }
    float t;
    t = __shfl_xor(r, 1, 64);  r = __fadd_rn(r, t);
    t = __shfl_xor(r, 2, 64);  r = __fadd_rn(r, t);
    t = __shfl_xor(r, 4, 64);  r = __fadd_rn(r, t);
    t = __shfl_xor(r, 8, 64);  r = __fadd_rn(r, t);
    if (sub == 0) dst[row] = r;
}

// ---------------- K1: fp32 dist + first-index argmin -----------------------
// 512 threads/block; per-thread acc 4 rows x 8 cols (32 VGPRs) so total live
// set ~100 VGPRs -> stays under the 128-VGPR wave-budget step (R4: 136 VGPRs
// halved waves/SIMD to 2; R3: (256,4) clamp to 64 spilled 1.1 GB).
// Split-K: blockIdx.y in {0,1} -> cols [y*512, y*512+512); 32 (cb,dc) tiles.
// LDS row-major stride 36: conflict-free b128 staging, broadcast-heavy reads.
// Staging is software-pipelined: tile t+1's global loads issue before tile
// t's compute. acc[i][j] = single ascending-d fmaf chain = OpenBLAS bits.
// R5 BUG (fixed): merge scratch Mi was sm+2048*4 (float-ptr math -> byte
// 32768, overran the 36864 B LDS block by 4 KB -> garbage indices). Mi must
// be sm+2048 floats = byte 8192.
#define TM 128
#define TN 128
#define TD 32
#define STR 36          // floats; 144 B row stride, 16B-aligned

__global__ __launch_bounds__(512) void k_pass1(
    const float* __restrict__ X, const float* __restrict__ E,
    const float* __restrict__ B32, const float* __restrict__ Arr,
    unsigned long long* __restrict__ packed)
{
    __shared__ float sm[2 * TM * STR];   // 36864 B -> 2 blocks/CU (LDS-wise)
    float* Xs = sm;                      // [128][36]
    float* Es = sm + TM * STR;           // [128][36]

    const int tid = threadIdx.x;
    const int tx = tid & 15;             // col group: owns cols tx+16j, j<8
    const int ty = tid >> 4;             // 0..31: owns rows ty+32i, i<4
    const int rowbase = blockIdx.x * TM;
    const int colbase = blockIdx.y * 512;

    // staging decomposition: thread stages 2 float4 of X and 2 of E per tile
    const int sr = tid >> 3;             // 0..63
    const int sg = (tid & 7) * 4;        // 0,4,...,28

    float a8[4];
#pragma unroll
    for (int i = 0; i < 4; ++i) a8[i] = Arr[rowbase + ty + 32 * i];

    float v1[4]; int i1[4];
#pragma unroll
    for (int i = 0; i < 4; ++i) { v1[i] = 3.0e38f; i1[i] = 0; }

    float acc[4][8];
    float4 px0, px1, pe0, pe1;

    // preload tile 0 (cb=0, dc=0)
    px0 = *(const float4*)(X + (size_t)(rowbase + sr) * DIM + sg);
    px1 = *(const float4*)(X + (size_t)(rowbase + 64 + sr) * DIM + sg);
    pe0 = *(const float4*)(E + (size_t)(colbase + sr) * DIM + sg);
    pe1 = *(const float4*)(E + (size_t)(colbase + 64 + sr) * DIM + sg);

    for (int it = 0; it < 32; ++it) {
        const int cb = (it >> 3) * TN;       // 0,128,256,384
        if ((it & 7) == 0) {
#pragma unroll
            for (int i = 0; i < 4; ++i)
#pragma unroll
                for (int j = 0; j < 8; ++j) acc[i][j] = 0.0f;
        }

        __syncthreads();   // LDS free to overwrite
        *(float4*)&Xs[(sr)      * STR + sg] = px0;
        *(float4*)&Xs[(sr + 64) * STR + sg] = px1;
        *(float4*)&Es[(sr)      * STR + sg] = pe0;
        *(float4*)&Es[(sr + 64) * STR + sg] = pe1;

        // issue next tile's global loads (overlap with compute below)
        if (it + 1 < 32) {
            const int ncb = ((it + 1) >> 3) * TN;
            const int ndc = ((it + 1) & 7) * TD;
            px0 = *(const float4*)(X + (size_t)(rowbase + sr) * DIM + ndc + sg);
            px1 = *(const float4*)(X + (size_t)(rowbase + 64 + sr) * DIM + ndc + sg);
            pe0 = *(const float4*)(E + (size_t)(colbase + ncb + sr) * DIM + ndc + sg);
            pe1 = *(const float4*)(E + (size_t)(colbase + ncb + 64 + sr) * DIM + ndc + sg);
        }
        __syncthreads();

#pragma unroll 2
        for (int gg = 0; gg < 8; ++gg) {
            float4 e4[8];
#pragma unroll
            for (int j = 0; j < 8; ++j)
                e4[j] = *(float4*)&Es[(tx + 16 * j) * STR + gg * 4];
#pragma unroll
            for (int i = 0; i < 4; ++i) {
                float4 x4 = *(float4*)&Xs[(ty + 32 * i) * STR + gg * 4];
#pragma unroll
                for (int j = 0; j < 8; ++j) {
                    acc[i][j] = fmaf(x4.x, e4[j].x, acc[i][j]);
                    acc[i][j] = fmaf(x4.y, e4[j].y, acc[i][j]);
                    acc[i][j] = fmaf(x4.z, e4[j].z, acc[i][j]);
                    acc[i][j] = fmaf(x4.w, e4[j].w, acc[i][j]);
                }
            }
        }

        if ((it & 7) == 7) {
            // fold: dist = fl(fl(A + B) - fl(2*dot)); strict < keeps lowest c
            // (c ascends with j and cb within a thread).
#pragma unroll
            for (int j = 0; j < 8; ++j) {
                int c = colbase + cb + tx + 16 * j;
                float b = B32[c];
#pragma unroll
                for (int i = 0; i < 4; ++i) {
                    float Cv  = __fmul_rn(2.0f, acc[i][j]);
                    float t1v = __fadd_rn(a8[i], b);
                    float dv  = __fsub_rn(t1v, Cv);
                    if (dv < v1[i]) { v1[i] = dv; i1[i] = c; }
                }
            }
        }
    }

    // merge (val, idx) across the 16 col-threads per row via LDS
    __syncthreads();
    float* Mv = sm;                        // [128][16] floats, bytes 0..8192
    int*   Mi = (int*)(sm + 2048);         // [128][16] ints, bytes 8192..16384
#pragma unroll
    for (int i = 0; i < 4; ++i) {
        int r = ty + 32 * i;
        Mv[r * 16 + tx] = v1[i];
        Mi[r * 16 + tx] = i1[i];
    }
    __syncthreads();
    if (tid < TM) {
        int r = tid;
        float bv = Mv[r * 16];
        int   bi = Mi[r * 16];
        for (int t = 1; t < 16; ++t) {
            float av = Mv[r * 16 + t];
            int   ai = Mi[r * 16 + t];
            if (av < bv || (av == bv && ai < bi)) { bv = av; bi = ai; }
        }
        // dist > 0 always (A ~ 256 dominates) -> IEEE bits order-preserving;
        // ties resolve to lower idx -> global first-index semantics.
        unsigned long long pk =
            ((unsigned long long)__float_as_uint(bv) << 32) |
            (unsigned long long)(unsigned)bi;
        atomicMin(&packed[rowbase + r], pk);
    }
}

// ---------------- K3: gather quantized + fp64 loss accumulation ------------
__global__ __launch_bounds__(256) void k_out(
    const float* __restrict__ X, const float* __restrict__ E,
    const unsigned long long* __restrict__ packed, float* __restrict__ out0,
    double* __restrict__ lossacc)
{
    const int NF4 = NQ / 4;
    double s = 0.0;
    for (int g = blockIdx.x * blockDim.x + threadIdx.x; g < NF4;
         g += gridDim.x * blockDim.x) {
        int row = g >> 6;
        int d4  = g & 63;
        int j = (int)(packed[row] & 0xffffffffULL);
        float4 q = *(const float4*)(E + (size_t)j * DIM + d4 * 4);
        float4 x = *(const float4*)(X + (size_t)g * 4);
        *(float4*)(out0 + (size_t)g * 4) = q;
        double dx;
        dx = (double)q.x - (double)x.x; s = fma(dx, dx, s);
        dx = (double)q.y - (double)x.y; s = fma(dx, dx, s);
        dx = (double)q.z - (double)x.z; s = fma(dx, dx, s);
        dx = (double)q.w - (double)x.w; s = fma(dx, dx, s);
    }
#pragma unroll
    for (int off = 32; off > 0; off >>= 1) s += __shfl_down(s, off, 64);
    __shared__ double wsum[4];
    int lane = threadIdx.x & 63, wv = threadIdx.x >> 6;
    if (lane == 0) wsum[wv] = s;
    __syncthreads();
    if (threadIdx.x == 0) {
        double t = wsum[0] + wsum[1] + wsum[2] + wsum[3];
        atomicAdd(lossacc, t);
    }
}

// ---------------- K3b: index output + histogram ----------------------------
__global__ __launch_bounds__(256) void k_idxout(
    const unsigned long long* __restrict__ packed, float* __restrict__ out1,
    int* __restrict__ counts)
{
    __shared__ int h[KC];
    for (int i = threadIdx.x; i < KC; i += 256) h[i] = 0;
    __syncthreads();
    int r = blockIdx.x * 256 + threadIdx.x;   // grid 256*256 = 65536 exact
    int j = (int)(packed[r] & 0xffffffffULL);
    out1[r] = (float)j;
    atomicAdd(&h[j], 1);
    __syncthreads();
    for (int i = threadIdx.x; i < KC; i += 256)
        if (h[i]) atomicAdd(&counts[i], h[i]);
}

// ---------------- K4: perplexity + loss finalize ---------------------------
__global__ void k_fin(const int* __restrict__ counts,
                      const double* __restrict__ lossacc,
                      float* __restrict__ out_pl)
{
    __shared__ double sh[256];
    double s = 0.0;
    for (int i = threadIdx.x; i < KC; i += 256) {
        double p = (double)counts[i] / 65536.0;
        s += p * log(p + 1.1920928955078125e-07);   // EPS = fp32 eps exactly
    }
    sh[threadIdx.x] = s;
    __syncthreads();
    for (int off = 128; off > 0; off >>= 1) {
        if (threadIdx.x < off) sh[threadIdx.x] += sh[threadIdx.x + off];
        __syncthreads();
    }
    if (threadIdx.x == 0) {
        out_pl[0] = (float)exp(-sh[0]);
        out_pl[1] = (float)((*lossacc / (double)NQ) * 1.1);  // q + 0.1*e
    }
}

extern "C" void kernel_launch(void* const* d_in, const int* in_sizes, int n_in,
                              void* d_out, int out_size, void* d_ws, size_t ws_size,
                              hipStream_t stream) {
    const float* X = (const float*)d_in[0];
    const float* E = (const float*)d_in[1];
    float* out = (float*)d_out;
    char* ws = (char*)d_ws;

    double* lossacc = (double*)(ws + 0);
    int*    counts  = (int*)(ws + 16);
    float*  B32     = (float*)(ws + 4224);
    float*  Arr     = (float*)(ws + 8320);
    unsigned long long* packed = (unsigned long long*)(ws + 270464);

    hipMemsetAsync(ws, 0, 4224, stream);               // lossacc + counts
    hipMemsetAsync(ws + 270464, 0xFF, 524288, stream); // packed = u64 max

    hipLaunchKernelGGL(k_prep16, dim3(KC / 16),   dim3(256), 0, stream,
                       E, B32, KC);
    hipLaunchKernelGGL(k_prep16, dim3(ROWS / 16), dim3(256), 0, stream,
                       X, Arr, ROWS);
    hipLaunchKernelGGL(k_pass1, dim3(ROWS / TM, 2), dim3(512), 0, stream,
                       X, E, B32, Arr, packed);
    hipLaunchKernelGGL(k_out,   dim3(2048), dim3(256), 0, stream,
                       X, E, packed, out, lossacc);
    hipLaunchKernelGGL(k_idxout, dim3(256), dim3(256), 0, stream,
                       packed, out + NQ, counts);
    hipLaunchKernelGGL(k_fin,   dim3(1),   dim3(256), 0, stream,
                       counts, lossacc, out + NQ + 65536);
}